// Round 1
// baseline (209.992 us; speedup 1.0000x reference)
//
#include <hip/hip_runtime.h>

typedef __attribute__((ext_vector_type(8))) __bf16 bf16x8;
typedef __attribute__((ext_vector_type(4))) float f32x4;
typedef __attribute__((ext_vector_type(8))) unsigned short us8;

constexpr float SCALE_L2E = 0.08838834764831845f * 1.4426950408889634f; // (1/sqrt(128))*log2(e)

__device__ __forceinline__ unsigned short f2bf(float f) {
  unsigned int u = __float_as_uint(f);
  u = (u + 0x7FFFu + ((u >> 16) & 1u)) >> 16;
  return (unsigned short)u;
}

__device__ __forceinline__ void gl_lds16(const void* g, void* l) {
  __builtin_amdgcn_global_load_lds(
      (__attribute__((address_space(1))) void*)const_cast<void*>(g),
      (__attribute__((address_space(3))) void*)l, 16, 0, 0);
}

// ---------------- K0: f32 -> bf16 convert (query + 3 weight matrices) ----------------
__global__ __launch_bounds__(256) void k_convert(
    const float* __restrict__ q, const float* __restrict__ wq,
    const float* __restrict__ wk, const float* __restrict__ wv,
    unsigned short* __restrict__ xb, unsigned short* __restrict__ wb) {
  long i = ((long)blockIdx.x * 256 + threadIdx.x) * 8;
  const float* s; unsigned short* d;
  if (i < 4194304)      { s = q  + i;             d = xb + i; }
  else if (i < 5242880) { s = wq + (i - 4194304); d = wb + (i - 4194304); }
  else if (i < 6291456) { s = wk + (i - 5242880); d = wb + 1048576 + (i - 5242880); }
  else                  { s = wv + (i - 6291456); d = wb + 2097152 + (i - 6291456); }
  float4 a = *(const float4*)s;
  float4 b = *(const float4*)(s + 4);
  us8 r;
  r[0]=f2bf(a.x); r[1]=f2bf(a.y); r[2]=f2bf(a.z); r[3]=f2bf(a.w);
  r[4]=f2bf(b.x); r[5]=f2bf(b.y); r[6]=f2bf(b.z); r[7]=f2bf(b.w);
  *(us8*)d = r;
}

// ---------------- K1: projection GEMM  C = X @ W^T + b  (z selects q/k/v) ----------------
// X: 4096x1024 bf16 row-major; W: 1024x1024 bf16 row-major (k contiguous) -> NT GEMM.
// q output gets the reverse-blade sign twist: sign = (col%8 < 4) ? +1 : -1.
__global__ __launch_bounds__(256) void k_proj(
    const unsigned short* __restrict__ xb, const unsigned short* __restrict__ wb,
    const float* __restrict__ bq, const float* __restrict__ bk, const float* __restrict__ bv,
    unsigned short* __restrict__ oq, unsigned short* __restrict__ ok_, unsigned short* __restrict__ ov) {
  __shared__ unsigned short As[4096]; // 128 rows x 32 k
  __shared__ unsigned short Bs[4096];
  const int t = threadIdx.x;
  const int wave = t >> 6, lane = t & 63;
  const int lrow = lane & 15, grp = lane >> 4;
  const int z = blockIdx.z;
  const unsigned short* w = wb + (size_t)z * 1048576;
  const float* bias = (z == 0) ? bq : ((z == 1) ? bk : bv);
  unsigned short* dst = (z == 0) ? oq : ((z == 1) ? ok_ : ov);

  const unsigned short* asrc = xb + ((size_t)(blockIdx.y * 128 + (t >> 2)) * 1024 + (t & 3) * 8);
  const unsigned short* bsrc = w  + ((size_t)(blockIdx.x * 128 + (t >> 2)) * 1024 + (t & 3) * 8);

  f32x4 acc[4][4] = {};
  for (int kt = 0; kt < 32; ++kt) {
    gl_lds16(asrc + kt*32,              &As[t*8]);
    gl_lds16(asrc + kt*32 + 64*1024,    &As[2048 + t*8]);
    gl_lds16(bsrc + kt*32,              &Bs[t*8]);
    gl_lds16(bsrc + kt*32 + 64*1024,    &Bs[2048 + t*8]);
    __syncthreads();
    const int wr = wave >> 1, wc = wave & 1;
    bf16x8 af[4], bf[4];
#pragma unroll
    for (int mf = 0; mf < 4; ++mf)
      af[mf] = *(const bf16x8*)&As[(wr*64 + mf*16 + lrow)*32 + grp*8];
#pragma unroll
    for (int nf = 0; nf < 4; ++nf)
      bf[nf] = *(const bf16x8*)&Bs[(wc*64 + nf*16 + lrow)*32 + grp*8];
#pragma unroll
    for (int mf = 0; mf < 4; ++mf)
#pragma unroll
      for (int nf = 0; nf < 4; ++nf)
        acc[mf][nf] = __builtin_amdgcn_mfma_f32_16x16x32_bf16(af[mf], bf[nf], acc[mf][nf], 0, 0, 0);
    __syncthreads();
  }
  const int wr = wave >> 1, wc = wave & 1;
  const float sign = (z == 0 && (lane & 7) >= 4) ? -1.0f : 1.0f;
#pragma unroll
  for (int nf = 0; nf < 4; ++nf) {
    const int col = blockIdx.x*128 + wc*64 + nf*16 + lrow;
    const float bsv = bias[col];
#pragma unroll
    for (int mf = 0; mf < 4; ++mf)
#pragma unroll
      for (int i = 0; i < 4; ++i) {
        const int row = blockIdx.y*128 + wr*64 + mf*16 + grp*4 + i;
        dst[(size_t)row*1024 + col] = f2bf((acc[mf][nf][i] + bsv) * sign);
      }
  }
}

// ---------------- K2: transpose v (per b,h: [L][128] -> [128][L]) ----------------
__global__ __launch_bounds__(256) void k_transp(const unsigned short* __restrict__ v,
                                                unsigned short* __restrict__ vt) {
  const int lt = blockIdx.x;   // 0..31
  const int bh = blockIdx.y;   // 0..15
  const int b = bh >> 3, h = bh & 7;
  const int t = threadIdx.x;
  const int d = t & 127, lg = t >> 7;
  const int l0 = lt*64 + lg*32;
  unsigned short tmp[32];
  const unsigned short* src = v + ((size_t)(b*2048 + l0) * 1024 + h*128 + d);
#pragma unroll
  for (int j = 0; j < 32; ++j) tmp[j] = src[(size_t)j * 1024];
  unsigned short* dstp = vt + ((size_t)(bh*128 + d) * 2048 + l0);
#pragma unroll
  for (int j = 0; j < 4; ++j) {
    us8 r;
#pragma unroll
    for (int e = 0; e < 8; ++e) r[e] = tmp[j*8 + e];
    *(us8*)(dstp + j*8) = r;
  }
}

// ---------------- K3: fused attention out + rowsum (no-max online softmax) ----------------
// block = (b,h, 64 q-rows); 4 waves. Swapped QK^T: S^T = mfma(K,Q) so each lane holds
// 4 consecutive m for a fixed l -> cheap packed LDS write of P[l][m].
__global__ __launch_bounds__(256) void k_attn_out(
    const unsigned short* __restrict__ qw, const unsigned short* __restrict__ kb,
    const unsigned short* __restrict__ vt, float* __restrict__ outp,
    float* __restrict__ rsw) {
  __shared__ unsigned short P[64*72];   // [l][m], stride 72 (16B-aligned rows)
  __shared__ float red[320];            // [wave][64] partials + [256..319] inv
  const int lt = blockIdx.x;  // 0..31
  const int bh = blockIdx.y;  // 0..15
  const int b = bh >> 3, h = bh & 7;
  const int t = threadIdx.x;
  const int wave = t >> 6, lane = t & 63;
  const int lrow = lane & 15, grp = lane >> 4;

  const unsigned short* qb  = qw + ((size_t)b*2048*1024 + (size_t)h*128);
  const unsigned short* kbp = kb + ((size_t)b*2048*1024 + (size_t)h*128);
  const unsigned short* vtp = vt + ((size_t)bh*128*2048);

  // q fragments live in registers for the whole kernel (64 VGPRs)
  bf16x8 qf[4][4];
#pragma unroll
  for (int lf = 0; lf < 4; ++lf) {
    const size_t roff = (size_t)(lt*64 + lf*16 + lrow) * 1024;
#pragma unroll
    for (int ks = 0; ks < 4; ++ks)
      qf[lf][ks] = *(const bf16x8*)&qb[roff + ks*32 + grp*8];
  }

  f32x4 oacc[4][2] = {};
  float rs[4] = {0.f, 0.f, 0.f, 0.f};

  for (int mt = 0; mt < 32; ++mt) {
    bf16x8 kf[4];
    const size_t mrow = (size_t)(mt*64 + wave*16 + lrow) * 1024;
#pragma unroll
    for (int ks = 0; ks < 4; ++ks)
      kf[ks] = *(const bf16x8*)&kbp[mrow + ks*32 + grp*8];
    f32x4 s[4] = {};
#pragma unroll
    for (int ks = 0; ks < 4; ++ks)
#pragma unroll
      for (int lf = 0; lf < 4; ++lf)
        s[lf] = __builtin_amdgcn_mfma_f32_16x16x32_bf16(kf[ks], qf[lf][ks], s[lf], 0, 0, 0);
#pragma unroll
    for (int lf = 0; lf < 4; ++lf) {
      float e0 = __builtin_amdgcn_exp2f(s[lf][0] * SCALE_L2E);
      float e1 = __builtin_amdgcn_exp2f(s[lf][1] * SCALE_L2E);
      float e2 = __builtin_amdgcn_exp2f(s[lf][2] * SCALE_L2E);
      float e3 = __builtin_amdgcn_exp2f(s[lf][3] * SCALE_L2E);
      float ps = (e0 + e1) + (e2 + e3);
      ps += __shfl_xor(ps, 16, 64);
      ps += __shfl_xor(ps, 32, 64);
      rs[lf] += ps;
      uint2 pk;
      pk.x = (unsigned)f2bf(e0) | ((unsigned)f2bf(e1) << 16);
      pk.y = (unsigned)f2bf(e2) | ((unsigned)f2bf(e3) << 16);
      *(uint2*)&P[(lf*16 + lrow)*72 + wave*16 + grp*4] = pk;
    }
    __syncthreads();
    // PV: this wave owns d-slice [wave*32, wave*32+32)
#pragma unroll
    for (int ks2 = 0; ks2 < 2; ++ks2) {
      bf16x8 pa[4];
#pragma unroll
      for (int lf = 0; lf < 4; ++lf)
        pa[lf] = *(const bf16x8*)&P[(lf*16 + lrow)*72 + ks2*32 + grp*8];
#pragma unroll
      for (int df = 0; df < 2; ++df) {
        const int dd = wave*32 + df*16 + lrow;
        bf16x8 vf = *(const bf16x8*)&vtp[(size_t)dd*2048 + mt*64 + ks2*32 + grp*8];
#pragma unroll
        for (int lf = 0; lf < 4; ++lf)
          oacc[lf][df] = __builtin_amdgcn_mfma_f32_16x16x32_bf16(pa[lf], vf, oacc[lf][df], 0, 0, 0);
      }
    }
    __syncthreads();
  }
  if (lane < 16) {
#pragma unroll
    for (int lf = 0; lf < 4; ++lf) red[wave*64 + lf*16 + lane] = rs[lf];
  }
  __syncthreads();
  if (t < 64) {
    float tot = (red[t] + red[64+t]) + (red[128+t] + red[192+t]);
    rsw[(size_t)bh*2048 + lt*64 + t] = tot;
    red[256 + t] = 1.0f / tot;
  }
  __syncthreads();
#pragma unroll
  for (int lf = 0; lf < 4; ++lf)
#pragma unroll
    for (int i = 0; i < 4; ++i) {
      const int l = lf*16 + grp*4 + i;
      const float iv = red[256 + l];
      const size_t rowo = (size_t)(b*2048 + lt*64 + l) * 1024 + h*128;
#pragma unroll
      for (int df = 0; df < 2; ++df)
        outp[rowo + wave*32 + df*16 + lrow] = oacc[lf][df][i] * iv;
    }
}

// ---------------- K4: head-mean attention weights ----------------
// block = (b, 64 l-rows, 128 m-cols); h innermost, acc in registers, one write.
__global__ __launch_bounds__(256) void k_attn_mean(
    const unsigned short* __restrict__ qw, const unsigned short* __restrict__ kb,
    const float* __restrict__ rsw, float* __restrict__ meanp) {
  __shared__ float inv_s[512];  // [h][64 l]
  const int mt = blockIdx.x;   // 0..15
  const int lt = blockIdx.y;   // 0..31
  const int b  = blockIdx.z;   // 0..1
  const int t = threadIdx.x;
  const int wave = t >> 6, lane = t & 63;
  const int lrow = lane & 15, grp = lane >> 4;
  const int wl = wave >> 1, wm = wave & 1;

  {
    int idx = t;
#pragma unroll
    for (int rep = 0; rep < 2; ++rep, idx += 256) {
      int hh = idx >> 6, ll = idx & 63;
      inv_s[idx] = 1.0f / rsw[(size_t)(b*8 + hh)*2048 + lt*64 + ll];
    }
  }
  __syncthreads();

  f32x4 acc[2][4] = {};
  for (int h = 0; h < 8; ++h) {
    const unsigned short* qb = qw + ((size_t)b*2048*1024 + (size_t)h*128);
    const unsigned short* kp = kb + ((size_t)b*2048*1024 + (size_t)h*128);
    f32x4 s[2][4] = {};
#pragma unroll
    for (int ks = 0; ks < 4; ++ks) {
      bf16x8 qf[2], kf[4];
#pragma unroll
      for (int lf = 0; lf < 2; ++lf)
        qf[lf] = *(const bf16x8*)&qb[(size_t)(lt*64 + wl*32 + lf*16 + lrow)*1024 + ks*32 + grp*8];
#pragma unroll
      for (int mf = 0; mf < 4; ++mf)
        kf[mf] = *(const bf16x8*)&kp[(size_t)(mt*128 + wm*64 + mf*16 + lrow)*1024 + ks*32 + grp*8];
#pragma unroll
      for (int lf = 0; lf < 2; ++lf)
#pragma unroll
        for (int mf = 0; mf < 4; ++mf)
          s[lf][mf] = __builtin_amdgcn_mfma_f32_16x16x32_bf16(qf[lf], kf[mf], s[lf][mf], 0, 0, 0);
    }
#pragma unroll
    for (int lf = 0; lf < 2; ++lf) {
      float iv[4];
#pragma unroll
      for (int i = 0; i < 4; ++i)
        iv[i] = inv_s[h*64 + wl*32 + lf*16 + grp*4 + i];
#pragma unroll
      for (int mf = 0; mf < 4; ++mf)
#pragma unroll
        for (int i = 0; i < 4; ++i)
          acc[lf][mf][i] += __builtin_amdgcn_exp2f(s[lf][mf][i] * SCALE_L2E) * iv[i];
    }
  }
#pragma unroll
  for (int lf = 0; lf < 2; ++lf)
#pragma unroll
    for (int i = 0; i < 4; ++i) {
      const int l = lt*64 + wl*32 + lf*16 + grp*4 + i;
      const size_t rowo = (size_t)(b*2048 + l) * 2048;
#pragma unroll
      for (int mf = 0; mf < 4; ++mf)
        meanp[rowo + mt*128 + wm*64 + mf*16 + lrow] = acc[lf][mf][i] * 0.125f;
    }
}

extern "C" void kernel_launch(void* const* d_in, const int* in_sizes, int n_in,
                              void* d_out, int out_size, void* d_ws, size_t ws_size,
                              hipStream_t stream) {
  (void)in_sizes; (void)n_in; (void)out_size; (void)ws_size;
  const float* query = (const float*)d_in[0];
  const float* Wq = (const float*)d_in[1];
  const float* bq = (const float*)d_in[2];
  const float* Wk = (const float*)d_in[3];
  const float* bk = (const float*)d_in[4];
  const float* Wv = (const float*)d_in[5];
  const float* bv = (const float*)d_in[6];
  float* outp  = (float*)d_out;
  float* meanp = outp + 4194304;           // (B,L,DM) then (B,L,L)

  char* ws = (char*)d_ws;
  unsigned short* xb  = (unsigned short*)(ws);              // 8.4 MB
  unsigned short* wb  = (unsigned short*)(ws + 8388608);    // 6.3 MB (Wq,Wk,Wv)
  unsigned short* qws = (unsigned short*)(ws + 14680064);   // 8.4 MB (sign-twisted q)
  unsigned short* kws = (unsigned short*)(ws + 23068672);   // 8.4 MB
  unsigned short* vws = (unsigned short*)(ws + 31457280);   // 8.4 MB
  unsigned short* vtw = (unsigned short*)(ws + 39845888);   // 8.4 MB (v transposed)
  float*          rsw = (float*)(ws + 48234496);            // 128 KB rowsums

  k_convert<<<3584, 256, 0, stream>>>(query, Wq, Wk, Wv, xb, wb);
  k_proj<<<dim3(8, 32, 3), 256, 0, stream>>>(xb, wb, bq, bk, bv, qws, kws, vws);
  k_transp<<<dim3(32, 16), 256, 0, stream>>>(vws, vtw);
  k_attn_out<<<dim3(32, 16), 256, 0, stream>>>(qws, kws, vtw, outp, rsw);
  k_attn_mean<<<dim3(16, 32, 2), 256, 0, stream>>>(qws, kws, rsw, meanp);
}

// Round 2
// 165.857 us; speedup vs baseline: 1.2661x; 1.2661x over previous
//
#include <hip/hip_runtime.h>

typedef __attribute__((ext_vector_type(8))) __bf16 bf16x8;
typedef __attribute__((ext_vector_type(4))) float f32x4;
typedef __attribute__((ext_vector_type(8))) unsigned short us8;

constexpr float SCALE_L2E = 0.08838834764831845f * 1.4426950408889634f; // (1/sqrt(128))*log2(e)

__device__ __forceinline__ unsigned short f2bf(float f) {
  unsigned int u = __float_as_uint(f);
  u = (u + 0x7FFFu + ((u >> 16) & 1u)) >> 16;
  return (unsigned short)u;
}

__device__ __forceinline__ void gl_lds16(const void* g, void* l) {
  __builtin_amdgcn_global_load_lds(
      (__attribute__((address_space(1))) void*)const_cast<void*>(g),
      (__attribute__((address_space(3))) void*)l, 16, 0, 0);
}

// ---------------- K0: f32 -> bf16 convert (query + 3 weight matrices) ----------------
__global__ __launch_bounds__(256) void k_convert(
    const float* __restrict__ q, const float* __restrict__ wq,
    const float* __restrict__ wk, const float* __restrict__ wv,
    unsigned short* __restrict__ xb, unsigned short* __restrict__ wb) {
  long i = ((long)blockIdx.x * 256 + threadIdx.x) * 8;
  const float* s; unsigned short* d;
  if (i < 4194304)      { s = q  + i;             d = xb + i; }
  else if (i < 5242880) { s = wq + (i - 4194304); d = wb + (i - 4194304); }
  else if (i < 6291456) { s = wk + (i - 5242880); d = wb + 1048576 + (i - 5242880); }
  else                  { s = wv + (i - 6291456); d = wb + 2097152 + (i - 6291456); }
  float4 a = *(const float4*)s;
  float4 b = *(const float4*)(s + 4);
  us8 r;
  r[0]=f2bf(a.x); r[1]=f2bf(a.y); r[2]=f2bf(a.z); r[3]=f2bf(a.w);
  r[4]=f2bf(b.x); r[5]=f2bf(b.y); r[6]=f2bf(b.z); r[7]=f2bf(b.w);
  *(us8*)d = r;
}

// ---------------- K1: projection GEMM  C = X @ W^T + b  (z selects q/k/v) ----------------
__global__ __launch_bounds__(256) void k_proj(
    const unsigned short* __restrict__ xb, const unsigned short* __restrict__ wb,
    const float* __restrict__ bq, const float* __restrict__ bk, const float* __restrict__ bv,
    unsigned short* __restrict__ oq, unsigned short* __restrict__ ok_, unsigned short* __restrict__ ov) {
  __shared__ unsigned short As[4096]; // 128 rows x 32 k
  __shared__ unsigned short Bs[4096];
  const int t = threadIdx.x;
  const int wave = t >> 6, lane = t & 63;
  const int lrow = lane & 15, grp = lane >> 4;
  const int z = blockIdx.z;
  const unsigned short* w = wb + (size_t)z * 1048576;
  const float* bias = (z == 0) ? bq : ((z == 1) ? bk : bv);
  unsigned short* dst = (z == 0) ? oq : ((z == 1) ? ok_ : ov);

  const unsigned short* asrc = xb + ((size_t)(blockIdx.y * 128 + (t >> 2)) * 1024 + (t & 3) * 8);
  const unsigned short* bsrc = w  + ((size_t)(blockIdx.x * 128 + (t >> 2)) * 1024 + (t & 3) * 8);

  f32x4 acc[4][4] = {};
  for (int kt = 0; kt < 32; ++kt) {
    gl_lds16(asrc + kt*32,              &As[t*8]);
    gl_lds16(asrc + kt*32 + 64*1024,    &As[2048 + t*8]);
    gl_lds16(bsrc + kt*32,              &Bs[t*8]);
    gl_lds16(bsrc + kt*32 + 64*1024,    &Bs[2048 + t*8]);
    __syncthreads();
    const int wr = wave >> 1, wc = wave & 1;
    bf16x8 af[4], bf[4];
#pragma unroll
    for (int mf = 0; mf < 4; ++mf)
      af[mf] = *(const bf16x8*)&As[(wr*64 + mf*16 + lrow)*32 + grp*8];
#pragma unroll
    for (int nf = 0; nf < 4; ++nf)
      bf[nf] = *(const bf16x8*)&Bs[(wc*64 + nf*16 + lrow)*32 + grp*8];
#pragma unroll
    for (int mf = 0; mf < 4; ++mf)
#pragma unroll
      for (int nf = 0; nf < 4; ++nf)
        acc[mf][nf] = __builtin_amdgcn_mfma_f32_16x16x32_bf16(af[mf], bf[nf], acc[mf][nf], 0, 0, 0);
    __syncthreads();
  }
  const int wr = wave >> 1, wc = wave & 1;
  const float sign = (z == 0 && (lane & 7) >= 4) ? -1.0f : 1.0f;
#pragma unroll
  for (int nf = 0; nf < 4; ++nf) {
    const int col = blockIdx.x*128 + wc*64 + nf*16 + lrow;
    const float bsv = bias[col];
#pragma unroll
    for (int mf = 0; mf < 4; ++mf)
#pragma unroll
      for (int i = 0; i < 4; ++i) {
        const int row = blockIdx.y*128 + wr*64 + mf*16 + grp*4 + i;
        dst[(size_t)row*1024 + col] = f2bf((acc[mf][nf][i] + bsv) * sign);
      }
  }
}

// ---------------- K2: transpose v (per b,h: [L][128] -> [128][L]) ----------------
__global__ __launch_bounds__(256) void k_transp(const unsigned short* __restrict__ v,
                                                unsigned short* __restrict__ vt) {
  const int lt = blockIdx.x;   // 0..31
  const int bh = blockIdx.y;   // 0..15
  const int b = bh >> 3, h = bh & 7;
  const int t = threadIdx.x;
  const int d = t & 127, lg = t >> 7;
  const int l0 = lt*64 + lg*32;
  unsigned short tmp[32];
  const unsigned short* src = v + ((size_t)(b*2048 + l0) * 1024 + h*128 + d);
#pragma unroll
  for (int j = 0; j < 32; ++j) tmp[j] = src[(size_t)j * 1024];
  unsigned short* dstp = vt + ((size_t)(bh*128 + d) * 2048 + l0);
#pragma unroll
  for (int j = 0; j < 4; ++j) {
    us8 r;
#pragma unroll
    for (int e = 0; e < 8; ++e) r[e] = tmp[j*8 + e];
    *(us8*)(dstp + j*8) = r;
  }
}

// ---------------- K3: fused attention out + rowsum (no-max online softmax) ----------------
__global__ __launch_bounds__(256) void k_attn_out(
    const unsigned short* __restrict__ qw, const unsigned short* __restrict__ kb,
    const unsigned short* __restrict__ vt, float* __restrict__ outp,
    float* __restrict__ rsw) {
  __shared__ unsigned short P[64*72];   // [l][m], stride 72 (16B-aligned rows)
  __shared__ float red[320];            // [wave][64] partials + [256..319] inv
  const int lt = blockIdx.x;  // 0..31
  const int bh = blockIdx.y;  // 0..15
  const int b = bh >> 3, h = bh & 7;
  const int t = threadIdx.x;
  const int wave = t >> 6, lane = t & 63;
  const int lrow = lane & 15, grp = lane >> 4;

  const unsigned short* qb  = qw + ((size_t)b*2048*1024 + (size_t)h*128);
  const unsigned short* kbp = kb + ((size_t)b*2048*1024 + (size_t)h*128);
  const unsigned short* vtp = vt + ((size_t)bh*128*2048);

  bf16x8 qf[4][4];
#pragma unroll
  for (int lf = 0; lf < 4; ++lf) {
    const size_t roff = (size_t)(lt*64 + lf*16 + lrow) * 1024;
#pragma unroll
    for (int ks = 0; ks < 4; ++ks)
      qf[lf][ks] = *(const bf16x8*)&qb[roff + ks*32 + grp*8];
  }

  f32x4 oacc[4][2] = {};
  float rs[4] = {0.f, 0.f, 0.f, 0.f};

  for (int mt = 0; mt < 32; ++mt) {
    bf16x8 kf[4];
    const size_t mrow = (size_t)(mt*64 + wave*16 + lrow) * 1024;
#pragma unroll
    for (int ks = 0; ks < 4; ++ks)
      kf[ks] = *(const bf16x8*)&kbp[mrow + ks*32 + grp*8];
    f32x4 s[4] = {};
#pragma unroll
    for (int ks = 0; ks < 4; ++ks)
#pragma unroll
      for (int lf = 0; lf < 4; ++lf)
        s[lf] = __builtin_amdgcn_mfma_f32_16x16x32_bf16(kf[ks], qf[lf][ks], s[lf], 0, 0, 0);
#pragma unroll
    for (int lf = 0; lf < 4; ++lf) {
      float e0 = __builtin_amdgcn_exp2f(s[lf][0] * SCALE_L2E);
      float e1 = __builtin_amdgcn_exp2f(s[lf][1] * SCALE_L2E);
      float e2 = __builtin_amdgcn_exp2f(s[lf][2] * SCALE_L2E);
      float e3 = __builtin_amdgcn_exp2f(s[lf][3] * SCALE_L2E);
      float ps = (e0 + e1) + (e2 + e3);
      ps += __shfl_xor(ps, 16, 64);
      ps += __shfl_xor(ps, 32, 64);
      rs[lf] += ps;
      uint2 pk;
      pk.x = (unsigned)f2bf(e0) | ((unsigned)f2bf(e1) << 16);
      pk.y = (unsigned)f2bf(e2) | ((unsigned)f2bf(e3) << 16);
      *(uint2*)&P[(lf*16 + lrow)*72 + wave*16 + grp*4] = pk;
    }
    __syncthreads();
#pragma unroll
    for (int ks2 = 0; ks2 < 2; ++ks2) {
      bf16x8 pa[4];
#pragma unroll
      for (int lf = 0; lf < 4; ++lf)
        pa[lf] = *(const bf16x8*)&P[(lf*16 + lrow)*72 + ks2*32 + grp*8];
#pragma unroll
      for (int df = 0; df < 2; ++df) {
        const int dd = wave*32 + df*16 + lrow;
        bf16x8 vf = *(const bf16x8*)&vtp[(size_t)dd*2048 + mt*64 + ks2*32 + grp*8];
#pragma unroll
        for (int lf = 0; lf < 4; ++lf)
          oacc[lf][df] = __builtin_amdgcn_mfma_f32_16x16x32_bf16(pa[lf], vf, oacc[lf][df], 0, 0, 0);
      }
    }
    __syncthreads();
  }
  if (lane < 16) {
#pragma unroll
    for (int lf = 0; lf < 4; ++lf) red[wave*64 + lf*16 + lane] = rs[lf];
  }
  __syncthreads();
  if (t < 64) {
    float tot = (red[t] + red[64+t]) + (red[128+t] + red[192+t]);
    rsw[(size_t)bh*2048 + lt*64 + t] = tot;
    red[256 + t] = 1.0f / tot;
  }
  __syncthreads();
#pragma unroll
  for (int lf = 0; lf < 4; ++lf)
#pragma unroll
    for (int i = 0; i < 4; ++i) {
      const int l = lf*16 + grp*4 + i;
      const float iv = red[256 + l];
      const size_t rowo = (size_t)(b*2048 + lt*64 + l) * 1024 + h*128;
#pragma unroll
      for (int df = 0; df < 2; ++df)
        outp[rowo + wave*32 + df*16 + lrow] = oacc[lf][df][i] * iv;
    }
}

// ---------------- K4: head-mean attention weights (LDS-staged GEMM version) ----------------
// block = 128 l x 128 m tile for one b; 4 waves (2x2 of 64x64); h loop with
// Q/K tiles staged via global_load_lds. LDS row stride 256B would be a 16-way
// bank conflict on ds_read_b128 -> both-sides XOR swizzle (16B granule, row&7):
// global source column pre-swizzled, LDS dest linear, read XORs the same mask.
__global__ __launch_bounds__(256) void k_attn_mean(
    const unsigned short* __restrict__ qw, const unsigned short* __restrict__ kb,
    const float* __restrict__ rsw, float* __restrict__ meanp) {
  __shared__ unsigned short Qs[128*128];   // 32 KB
  __shared__ unsigned short Ks[128*128];   // 32 KB
  __shared__ float inv_s[8*128];           // 4 KB
  const int mt = blockIdx.x;   // 0..15
  const int lt = blockIdx.y;   // 0..15
  const int b  = blockIdx.z;   // 0..1
  const int t = threadIdx.x;
  const int wave = t >> 6, lane = t & 63;
  const int lrow = lane & 15, grp = lane >> 4;
  const int wl = wave >> 1, wm = wave & 1;
  const int trow = t >> 4;     // 0..15 (staging row-within-16)
  const int tcol = t & 15;     // staging 16B-granule column

  for (int idx = t; idx < 1024; idx += 256) {
    int hh = idx >> 7, ll = idx & 127;
    inv_s[idx] = 1.0f / rsw[(size_t)(b*8 + hh)*2048 + lt*128 + ll];
  }

  f32x4 acc[4][4] = {};

  for (int h = 0; h < 8; ++h) {
    __syncthreads();   // previous iteration's LDS reads done (also fences inv_s at h=0)
    const unsigned short* qbase = qw + ((size_t)(b*2048 + lt*128) * 1024 + h*128);
    const unsigned short* kbase = kb + ((size_t)(b*2048 + mt*128) * 1024 + h*128);
#pragma unroll
    for (int i = 0; i < 8; ++i) {
      const int row = i*16 + trow;
      const int sc = (tcol ^ (row & 7)) * 8;   // swizzled source col (us units)
      gl_lds16(qbase + (size_t)row*1024 + sc, &Qs[i*2048 + t*8]);
      gl_lds16(kbase + (size_t)row*1024 + sc, &Ks[i*2048 + t*8]);
    }
    __syncthreads();   // staging complete (compiler drains vmcnt before barrier)

    f32x4 s[4][4] = {};
#pragma unroll
    for (int ks = 0; ks < 4; ++ks) {
      bf16x8 af[4], bf[4];
#pragma unroll
      for (int lf = 0; lf < 4; ++lf) {
        const int row = wl*64 + lf*16 + lrow;
        af[lf] = *(const bf16x8*)&Qs[row*128 + ((ks*32 + grp*8) ^ ((row & 7) << 3))];
      }
#pragma unroll
      for (int mf = 0; mf < 4; ++mf) {
        const int row = wm*64 + mf*16 + lrow;
        bf[mf] = *(const bf16x8*)&Ks[row*128 + ((ks*32 + grp*8) ^ ((row & 7) << 3))];
      }
#pragma unroll
      for (int lf = 0; lf < 4; ++lf)
#pragma unroll
        for (int mf = 0; mf < 4; ++mf)
          s[lf][mf] = __builtin_amdgcn_mfma_f32_16x16x32_bf16(af[lf], bf[mf], s[lf][mf], 0, 0, 0);
    }
#pragma unroll
    for (int lf = 0; lf < 4; ++lf)
#pragma unroll
      for (int i = 0; i < 4; ++i) {
        const float iv = inv_s[h*128 + wl*64 + lf*16 + grp*4 + i];
#pragma unroll
        for (int mf = 0; mf < 4; ++mf)
          acc[lf][mf][i] += __builtin_amdgcn_exp2f(s[lf][mf][i] * SCALE_L2E) * iv;
      }
  }

#pragma unroll
  for (int lf = 0; lf < 4; ++lf)
#pragma unroll
    for (int i = 0; i < 4; ++i) {
      const int l = lt*128 + wl*64 + lf*16 + grp*4 + i;
      const size_t rowo = (size_t)(b*2048 + l) * 2048;
#pragma unroll
      for (int mf = 0; mf < 4; ++mf)
        meanp[rowo + mt*128 + wm*64 + mf*16 + lrow] = acc[lf][mf][i] * 0.125f;
    }
}

extern "C" void kernel_launch(void* const* d_in, const int* in_sizes, int n_in,
                              void* d_out, int out_size, void* d_ws, size_t ws_size,
                              hipStream_t stream) {
  (void)in_sizes; (void)n_in; (void)out_size; (void)ws_size;
  const float* query = (const float*)d_in[0];
  const float* Wq = (const float*)d_in[1];
  const float* bq = (const float*)d_in[2];
  const float* Wk = (const float*)d_in[3];
  const float* bk = (const float*)d_in[4];
  const float* Wv = (const float*)d_in[5];
  const float* bv = (const float*)d_in[6];
  float* outp  = (float*)d_out;
  float* meanp = outp + 4194304;           // (B,L,DM) then (B,L,L)

  char* ws = (char*)d_ws;
  unsigned short* xb  = (unsigned short*)(ws);              // 8.4 MB
  unsigned short* wb  = (unsigned short*)(ws + 8388608);    // 6.3 MB (Wq,Wk,Wv)
  unsigned short* qws = (unsigned short*)(ws + 14680064);   // 8.4 MB (sign-twisted q)
  unsigned short* kws = (unsigned short*)(ws + 23068672);   // 8.4 MB
  unsigned short* vws = (unsigned short*)(ws + 31457280);   // 8.4 MB
  unsigned short* vtw = (unsigned short*)(ws + 39845888);   // 8.4 MB (v transposed)
  float*          rsw = (float*)(ws + 48234496);            // 128 KB rowsums

  k_convert<<<3584, 256, 0, stream>>>(query, Wq, Wk, Wv, xb, wb);
  k_proj<<<dim3(8, 32, 3), 256, 0, stream>>>(xb, wb, bq, bk, bv, qws, kws, vws);
  k_transp<<<dim3(32, 16), 256, 0, stream>>>(vws, vtw);
  k_attn_out<<<dim3(32, 16), 256, 0, stream>>>(qws, kws, vtw, outp, rsw);
  k_attn_mean<<<dim3(16, 16, 2), 256, 0, stream>>>(qws, kws, rsw, meanp);
}